// Round 2
// baseline (49.190 us; speedup 1.0000x reference)
//
#include <hip/hip_runtime.h>
#include <hip/hip_bf16.h>

// Conv encoder, rate 1/2, constraint length 3, GEN_POLY = ("101", "111").
//   c0[t] = u[t] ^ u[t-2]
//   c1[t] = u[t] ^ u[t-1] ^ u[t-2]     (u[-1] = u[-2] = 0 per row)
// Output interleaved per row: out[b, 2t] = c0, out[b, 2t+1] = c1.
//
// Layout trick: input rows are K=2048 (power of 2), output rows are 2K.
// For flat input index e, flat output index is exactly 2e — no div/mod.
// Row boundary (for the 2-bit lookback) is just (e & (K-1)) == 0.
//
// Each thread: 8 consecutive elements -> 32 B load + 64 B store, fully
// coalesced; 2 scalar L1-hit lookback loads only at non-row-start chunks.

#define K_LOG2 11
#define K_MASK 2047

__global__ __launch_bounds__(256) void conv_enc_kernel(
    const float* __restrict__ in, float* __restrict__ out) {
    long tid = (long)blockIdx.x * blockDim.x + threadIdx.x;
    long e0 = tid << 3;                        // first of 8 elements

    const float4* p = reinterpret_cast<const float4*>(in + e0);
    float4 va = p[0];
    float4 vb = p[1];

    float pm1 = 0.0f, pm2 = 0.0f;
    if ((e0 & K_MASK) != 0) {                  // not a row start
        pm1 = in[e0 - 1];                      // u[t0-1]
        pm2 = in[e0 - 2];                      // u[t0-2]
    }

    // u[0..1] = lookback, u[2..9] = the 8 current bits
    int u0 = (int)pm2, u1 = (int)pm1;
    int u2 = (int)va.x, u3 = (int)va.y, u4 = (int)va.z, u5 = (int)va.w;
    int u6 = (int)vb.x, u7 = (int)vb.y, u8 = (int)vb.z, u9 = (int)vb.w;

    // c0_i = u[i+2] ^ u[i];  c1_i = u[i+2] ^ u[i+1] ^ u[i]
    float4 o0 = make_float4((float)(u2 ^ u0), (float)(u2 ^ u1 ^ u0),
                            (float)(u3 ^ u1), (float)(u3 ^ u2 ^ u1));
    float4 o1 = make_float4((float)(u4 ^ u2), (float)(u4 ^ u3 ^ u2),
                            (float)(u5 ^ u3), (float)(u5 ^ u4 ^ u3));
    float4 o2 = make_float4((float)(u6 ^ u4), (float)(u6 ^ u5 ^ u4),
                            (float)(u7 ^ u5), (float)(u7 ^ u6 ^ u5));
    float4 o3 = make_float4((float)(u8 ^ u6), (float)(u8 ^ u7 ^ u6),
                            (float)(u9 ^ u7), (float)(u9 ^ u8 ^ u7));

    float4* q = reinterpret_cast<float4*>(out + (e0 << 1));
    q[0] = o0;
    q[1] = o1;
    q[2] = o2;
    q[3] = o3;
}

extern "C" void kernel_launch(void* const* d_in, const int* in_sizes, int n_in,
                              void* d_out, int out_size, void* d_ws, size_t ws_size,
                              hipStream_t stream) {
    const float* in = (const float*)d_in[0];
    float* out = (float*)d_out;

    // B*K = 16,777,216 elements; 8 per thread -> 2,097,152 threads
    long total_threads = (long)in_sizes[0] / 8;
    int block = 256;
    int grid = (int)((total_threads + block - 1) / block);   // 8192

    conv_enc_kernel<<<grid, block, 0, stream>>>(in, out);
}

// Round 3
// 36.194 us; speedup vs baseline: 1.3591x; 1.3591x over previous
//
#include <hip/hip_runtime.h>
#include <hip/hip_bf16.h>

// Conv encoder, rate 1/2, constraint length 3, GEN_POLY = ("101", "111").
//   c0[t] = u[t] ^ u[t-2]
//   c1[t] = u[t] ^ u[t-1] ^ u[t-2]     (u[-1] = u[-2] = 0 per row)
// out[b, 2t] = c0, out[b, 2t+1] = c1;  flat out index = 2 * flat in index.
//
// Bits are 0.0f / 1.0f. {0x00000000, 0x3F800000} is closed under XOR, so we
// XOR raw bit patterns — zero int<->float conversions.
//
// Each thread: 2 input elements (uint2, 8 B/lane packed load) -> 4 output
// elements (uint4, 16 B/lane packed store). Lookback u[t-1],u[t-2] come from
// the previous lane via __shfl_up; only lane 0 reads memory (row starts are
// wave-aligned: K=2048 -> row start iff tid % 1024 == 0, always lane 0).

#define K_MASK 2047

__global__ __launch_bounds__(256) void conv_enc_kernel(
    const unsigned int* __restrict__ in, unsigned int* __restrict__ out) {
    long tid = (long)blockIdx.x * blockDim.x + threadIdx.x;
    long e0 = tid << 1;                                  // first input element

    uint2 v = reinterpret_cast<const uint2*>(in)[tid];   // u[e0], u[e0+1]

    unsigned int p2 = __shfl_up(v.x, 1);                 // u[e0-2]
    unsigned int p1 = __shfl_up(v.y, 1);                 // u[e0-1]
    if ((threadIdx.x & 63) == 0) {
        if ((e0 & K_MASK) == 0) {                        // row start
            p1 = 0u; p2 = 0u;
        } else {                                         // cross-wave lookback
            p1 = in[e0 - 1];
            p2 = in[e0 - 2];
        }
    }

    uint4 o;
    o.x = v.x ^ p2;                  // c0[t]   = u[t]   ^ u[t-2]
    o.y = o.x ^ p1;                  // c1[t]   = u[t]   ^ u[t-1] ^ u[t-2]
    o.z = v.y ^ p1;                  // c0[t+1] = u[t+1] ^ u[t-1]
    o.w = o.z ^ v.x;                 // c1[t+1] = u[t+1] ^ u[t]   ^ u[t-1]

    reinterpret_cast<uint4*>(out)[tid] = o;
}

extern "C" void kernel_launch(void* const* d_in, const int* in_sizes, int n_in,
                              void* d_out, int out_size, void* d_ws, size_t ws_size,
                              hipStream_t stream) {
    const unsigned int* in = (const unsigned int*)d_in[0];
    unsigned int* out = (unsigned int*)d_out;

    long total_threads = (long)in_sizes[0] / 2;          // 8,388,608
    int block = 256;
    int grid = (int)((total_threads + block - 1) / block);   // 32768

    conv_enc_kernel<<<grid, block, 0, stream>>>(in, out);
}